// Round 6
// baseline (6771.884 us; speedup 1.0000x reference)
//
#include <hip/hip_runtime.h>

#define BHN   16
#define NSEQ  4096
#define DD    64
#define QT    32            // query rows per block
#define KT    64            // key rows per tile
#define QBLK  (NSEQ / QT)   // 128 query tiles per bh

// ---------------------------------------------------------------------------
// norm: inverse L2 norm per row (fp32)
// grid 256 x 256 threads, one thread per row (16*4096 rows)
// ---------------------------------------------------------------------------
__global__ void ContentGCN_5059471475267_norm(const float* __restrict__ src,
                                              float* __restrict__ invn)
{
    int row = blockIdx.x * 256 + threadIdx.x;          // 0 .. 65535
    const float* p = src + (size_t)row * DD;
    float ss = 0.f;
    for (int d = 0; d < DD; d++) { float f = p[d]; ss += f * f; }
    float n = sqrtf(ss);
    if (n < 1e-12f) n = 1e-12f;                        // F.normalize eps
    invn[row] = 1.0f / n;
}

// ---------------------------------------------------------------------------
// attn: flash attention, Q=K=normalize(x), V=x, then out = relu(av@W^T + x)
// grid BHN*QBLK x 256. r = tid>>3 (query row 0..31), dg = tid&7 (8 cols/dims).
// All fp32. src != out in both layers (no aliasing).
// ---------------------------------------------------------------------------
__global__ void ContentGCN_5059471475267_attn(
    const float* __restrict__ xsrc, const float* __restrict__ invn,
    const float* __restrict__ Wt, const float* __restrict__ alphap,
    float* __restrict__ out)
{
    __shared__ float sQ[QT][DD + 1];
    __shared__ float sX[KT][DD + 1];
    __shared__ float sS[QT][DD + 1];
    __shared__ float sW[DD][DD + 1];
    __shared__ float sRm[QT][8];
    __shared__ float sRs[QT][8];
    __shared__ float sIq[QT];
    __shared__ float sIk[KT];

    int tid = threadIdx.x;
    int r   = tid >> 3;        // 0..31
    int dg  = tid & 7;
    int d0  = dg * 8;
    int bh  = blockIdx.x >> 7; // QBLK = 128
    int qt  = blockIdx.x & 127;

    float alpha = alphap[0];
    float scl = 1.4426950408889634f / fmaxf(alpha, 0.01f);   // exp2 domain

    size_t bbase = (size_t)bh * NSEQ;
    size_t qrow0 = bbase + (size_t)qt * QT;

    // stage Q tile and W (once)
    for (int i = tid; i < QT * DD; i += 256) {
        int rr = i >> 6, cc = i & 63;
        sQ[rr][cc] = xsrc[(qrow0 + rr) * DD + cc];
    }
    for (int i = tid; i < DD * DD; i += 256) {
        int rr = i >> 6, cc = i & 63;
        sW[rr][cc] = Wt[(size_t)rr * DD + cc];
    }
    if (tid < QT) sIq[tid] = invn[qrow0 + tid];
    __syncthreads();

    float m = -1e30f, l = 0.f;
    float av[8];
    for (int k = 0; k < 8; k++) av[k] = 0.f;

    for (int kt = 0; kt < NSEQ / KT; kt++) {
        __syncthreads();   // all PV reads of previous sX done
        for (int i = tid; i < KT * DD; i += 256) {
            int rr = i >> 6, cc = i & 63;
            sX[rr][cc] = xsrc[(bbase + (size_t)kt * KT + rr) * DD + cc];
        }
        if (tid < KT) sIk[tid] = invn[bbase + (size_t)kt * KT + tid];
        __syncthreads();

        // scores for 8 cols j = d0 + jj  (d-outer: 9 LDS reads / 8 FMAs)
        float acc[8];
        for (int jj = 0; jj < 8; jj++) acc[jj] = 0.f;
        for (int d = 0; d < DD; d++) {
            float q = sQ[r][d];
            for (int jj = 0; jj < 8; jj++) acc[jj] += q * sX[d0 + jj][d];
        }
        float iq = sIq[r];
        for (int jj = 0; jj < 8; jj++) acc[jj] = acc[jj] * iq * sIk[d0 + jj] * scl;

        float mloc = acc[0];
        for (int jj = 1; jj < 8; jj++) mloc = fmaxf(mloc, acc[jj]);
        sRm[r][dg] = mloc;
        __syncthreads();
        float mt = sRm[r][0];
        for (int t = 1; t < 8; t++) mt = fmaxf(mt, sRm[r][t]);
        float mnew = fmaxf(m, mt);
        float corr = exp2f(m - mnew);
        m = mnew;
        float psum = 0.f;
        for (int jj = 0; jj < 8; jj++) {
            float p = exp2f(acc[jj] - mnew);
            sS[r][d0 + jj] = p;
            psum += p;
        }
        sRs[r][dg] = psum;
        __syncthreads();
        float lt = 0.f;
        for (int t = 0; t < 8; t++) lt += sRs[r][t];
        l = l * corr + lt;

        // PV: av[k] += sum_j p[j] * V[j][d0+k]
        for (int k = 0; k < 8; k++) av[k] *= corr;
        for (int j = 0; j < KT; j++) {
            float pj = sS[r][j];
            for (int k = 0; k < 8; k++) av[k] += pj * sX[j][d0 + k];
        }
    }

    // epilogue: av/l -> sS row; out = relu(av @ W^T + residual)
    float invl = 1.0f / l;
    for (int k = 0; k < 8; k++) sS[r][d0 + k] = av[k] * invl;
    __syncthreads();

    for (int k = 0; k < 8; k++) {
        int e = d0 + k;
        float a = 0.f;
        for (int d = 0; d < DD; d++) a += sS[r][d] * sW[e][d];
        float v = a + xsrc[(qrow0 + r) * DD + e];
        out[(qrow0 + r) * DD + e] = (v < 0.f) ? 0.f : v;   // NaN-transparent relu
    }
}

extern "C" void kernel_launch(void* const* d_in, const int* in_sizes, int n_in,
                              void* d_out, int out_size, void* d_ws, size_t ws_size,
                              hipStream_t stream) {
    const float* x  = (const float*)d_in[0];
    const float* W1 = (const float*)d_in[1];
    const float* W2 = (const float*)d_in[2];
    const float* a1 = (const float*)d_in[3];
    const float* a2 = (const float*)d_in[4];
    float* outp = (float*)d_out;

    // ws: invn fp32 [65536] (256 KB) | y1 fp32 [4M] (16 MB)
    float* invn = (float*)d_ws;
    float* y1   = invn + (size_t)BHN * NSEQ;

    dim3 ngrid(BHN * NSEQ / 256), nblk(256);
    dim3 agrid(BHN * QBLK),       ablk(256);

    // layer 1: x -> y1
    ContentGCN_5059471475267_norm<<<ngrid, nblk, 0, stream>>>(x, invn);
    ContentGCN_5059471475267_attn<<<agrid, ablk, 0, stream>>>(x, invn, W1, a1, y1);
    // layer 2: y1 -> d_out
    ContentGCN_5059471475267_norm<<<ngrid, nblk, 0, stream>>>(y1, invn);
    ContentGCN_5059471475267_attn<<<agrid, ablk, 0, stream>>>(y1, invn, W2, a2, outp);
}

// Round 7
// 607.574 us; speedup vs baseline: 11.1458x; 11.1458x over previous
//
#include <hip/hip_runtime.h>

typedef unsigned short u16;
typedef __bf16 bf16x8 __attribute__((ext_vector_type(8)));  // MFMA A/B (4 VGPRs)
typedef float  f32x4  __attribute__((ext_vector_type(4)));  // MFMA C/D
typedef unsigned int u32;

#define BH    16
#define NSEQ  4096
#define DD    64
#define BM    64            // Q rows per block (4 waves x 16)
#define BN    64            // K rows per tile
#define LDP   72            // LDS row stride (u16): 144B; b128 access = uniform 8/bank (ideal)
#define QTILES (NSEQ / BM)  // 64

__device__ __forceinline__ float bf2f(u16 u) {
    union { u32 i; float f; } v; v.i = ((u32)u) << 16; return v.f;
}
__device__ __forceinline__ u16 f2bf(float f) {
    union { float f; u32 i; } v; v.f = f;
    u32 r = v.i + 0x7fffu + ((v.i >> 16) & 1u);   // RNE
    return (u16)(r >> 16);
}

// ---------------------------------------------------------------------------
// prep: L2-normalize rows -> xn (bf16); transpose raw values -> xT (bf16)
// src dtype: isf=1 fp32, isf=0 bf16(u16). grid BH*16 x 256 (1 row/thread)
// ---------------------------------------------------------------------------
__global__ __launch_bounds__(256) void ContentGCN_5059471475267_prep(
    const void* __restrict__ src, int isf,
    u16* __restrict__ xn, u16* __restrict__ xT)
{
    __shared__ u16 tile[256 * 65];
    int bh = blockIdx.x >> 4, nt = blockIdx.x & 15, tid = threadIdx.x;
    size_t row  = (size_t)bh * NSEQ + nt * 256 + tid;
    size_t base = row * DD;

    float v[64];
    if (isf) {
        const float4* g = (const float4*)((const float*)src + base);
#pragma unroll
        for (int i = 0; i < 16; i++) {
            float4 t4 = g[i];
            v[4*i] = t4.x; v[4*i+1] = t4.y; v[4*i+2] = t4.z; v[4*i+3] = t4.w;
        }
    } else {
        alignas(16) u16 tmp[64];
        const uint4* g = (const uint4*)((const u16*)src + base);
#pragma unroll
        for (int i = 0; i < 8; i++) ((uint4*)tmp)[i] = g[i];
#pragma unroll
        for (int d = 0; d < 64; d++) v[d] = bf2f(tmp[d]);
    }

    float ss = 0.f;
#pragma unroll
    for (int d = 0; d < 64; d++) ss += v[d] * v[d];
    float n = sqrtf(ss);
    if (n < 1e-12f) n = 1e-12f;            // F.normalize eps
    float inv = 1.0f / n;

    alignas(16) u16 nb[64];
#pragma unroll
    for (int d = 0; d < 64; d++) nb[d] = f2bf(v[d] * inv);
    uint4* gn = (uint4*)(xn + base);
#pragma unroll
    for (int i = 0; i < 8; i++) gn[i] = ((uint4*)nb)[i];

#pragma unroll
    for (int d = 0; d < 64; d++) tile[tid * 65 + d] = f2bf(v[d]);
    __syncthreads();

    int d = tid & 63, ch = tid >> 6;       // 4 chunks of 64 rows
    alignas(16) u16 ob[64];
#pragma unroll
    for (int nn = 0; nn < 64; nn++) ob[nn] = tile[(ch * 64 + nn) * 65 + d];
    uint4* gt = (uint4*)(xT + ((size_t)bh * DD + d) * NSEQ + (size_t)nt * 256 + ch * 64);
#pragma unroll
    for (int i = 0; i < 8; i++) gt[i] = ((uint4*)ob)[i];
}

// ---------------------------------------------------------------------------
// attn: MFMA flash attention (Q=K=xn, V=raw x) + out = relu(av@W^T + res)
// grid BH*QTILES x 256 (4 waves, 16-row strips). fp32 accum everywhere.
// res: isf-selected fp32/bf16; out: out_isf fp32 (d_out) or bf16 (ws y1).
// ---------------------------------------------------------------------------
__global__ __launch_bounds__(256) void ContentGCN_5059471475267_attn(
    const u16* __restrict__ xn, const u16* __restrict__ xT,
    const void* __restrict__ res, int res_isf,
    const float* __restrict__ Wt, const float* __restrict__ alphap,
    void* __restrict__ outp, int out_isf)
{
    __shared__ u16 sK[BN * LDP];
    __shared__ u16 sV[DD * LDP];        // V^T: [d][k]
    __shared__ u16 sP[4 * 16 * LDP];    // wave-private P strips
    __shared__ u16 sW[DD * LDP];

    int tid  = threadIdx.x;
    int wave = tid >> 6, lane = tid & 63;
    int quad = lane >> 4, l16 = lane & 15;
    int bh   = blockIdx.x >> 6;         // QTILES = 64
    int qt   = blockIdx.x & 63;

    float scale = 1.4426950408889634f / fmaxf(alphap[0], 0.01f);  // exp2 domain

    // stage W (fp32 -> bf16), 16 elems/thread
    {
        int r = tid >> 2, c0 = (tid & 3) * 16;
        alignas(16) u16 wb[16];
        const float4* gw = (const float4*)(Wt + r * DD + c0);
#pragma unroll
        for (int i = 0; i < 4; i++) {
            float4 t4 = gw[i];
            wb[4*i] = f2bf(t4.x); wb[4*i+1] = f2bf(t4.y);
            wb[4*i+2] = f2bf(t4.z); wb[4*i+3] = f2bf(t4.w);
        }
        *(uint4*)&sW[r * LDP + c0]     = ((uint4*)wb)[0];
        *(uint4*)&sW[r * LDP + c0 + 8] = ((uint4*)wb)[1];
    }

    // Q fragments (A-layout: m=l16, k=quad*8+j)
    int qrow = qt * BM + wave * 16 + l16;
    size_t qbase = ((size_t)bh * NSEQ + qrow) * DD;
    bf16x8 aQ0 = *(const bf16x8*)(xn + qbase + quad * 8);
    bf16x8 aQ1 = *(const bf16x8*)(xn + qbase + 32 + quad * 8);

    const f32x4 fzero = {0.f, 0.f, 0.f, 0.f};
    f32x4 O[4];
#pragma unroll
    for (int t = 0; t < 4; t++) O[t] = fzero;
    float m_r[4], l_r[4];
#pragma unroll
    for (int r = 0; r < 4; r++) { m_r[r] = -1e30f; l_r[r] = 0.f; }

    u16* sPw = sP + wave * (16 * LDP);
    int srow = tid >> 2, scol = (tid & 3) * 16;     // staging: 16 elems/thread
    size_t kbase = (size_t)bh * NSEQ;

    for (int kt = 0; kt < NSEQ / BN; kt++) {
        __syncthreads();   // prior iter's LDS reads complete before overwrite
        {
            const uint4* gk = (const uint4*)(xn + (kbase + (size_t)kt * BN + srow) * DD + scol);
            uint4 k0 = gk[0], k1 = gk[1];
            const uint4* gv = (const uint4*)(xT + ((size_t)bh * DD + srow) * NSEQ + (size_t)kt * BN + scol);
            uint4 v0 = gv[0], v1 = gv[1];
            *(uint4*)&sK[srow * LDP + scol]     = k0;
            *(uint4*)&sK[srow * LDP + scol + 8] = k1;
            *(uint4*)&sV[srow * LDP + scol]     = v0;
            *(uint4*)&sV[srow * LDP + scol + 8] = v1;
        }
        __syncthreads();

        // S = Qn @ Kn^T (16 rows x 64 cols per wave)
        f32x4 S[4];
#pragma unroll
        for (int t = 0; t < 4; t++) {
            bf16x8 b0 = *(const bf16x8*)&sK[(l16 + 16 * t) * LDP + quad * 8];
            bf16x8 b1 = *(const bf16x8*)&sK[(l16 + 16 * t) * LDP + 32 + quad * 8];
            f32x4 acc = fzero;
            acc = __builtin_amdgcn_mfma_f32_16x16x32_bf16(aQ0, b0, acc, 0, 0, 0);
            acc = __builtin_amdgcn_mfma_f32_16x16x32_bf16(aQ1, b1, acc, 0, 0, 0);
            S[t] = acc;
        }

        // online softmax; C-layout: col=l16+16t, row=quad*4+r
#pragma unroll
        for (int r = 0; r < 4; r++) {
            float v = fmaxf(fmaxf(S[0][r], S[1][r]), fmaxf(S[2][r], S[3][r]));
            v = fmaxf(v, __shfl_xor(v, 1));
            v = fmaxf(v, __shfl_xor(v, 2));
            v = fmaxf(v, __shfl_xor(v, 4));
            v = fmaxf(v, __shfl_xor(v, 8));
            float mnew = fmaxf(m_r[r], v * scale);
            float corr = exp2f(m_r[r] - mnew);
            m_r[r] = mnew;
            float rs = 0.f;
#pragma unroll
            for (int t = 0; t < 4; t++) {
                float p = exp2f(S[t][r] * scale - mnew);
                u16 pb = f2bf(p);
                sPw[(quad * 4 + r) * LDP + l16 + 16 * t] = pb;
                rs += bf2f(pb);            // consistent with MFMA's bf16 P
            }
            rs += __shfl_xor(rs, 1);
            rs += __shfl_xor(rs, 2);
            rs += __shfl_xor(rs, 4);
            rs += __shfl_xor(rs, 8);
            l_r[r] = l_r[r] * corr + rs;
#pragma unroll
            for (int t = 0; t < 4; t++) O[t][r] *= corr;
        }

        // PV: A = P (LDS round-trip to A-layout), B = V^T rows
        bf16x8 aP0 = *(const bf16x8*)&sPw[l16 * LDP + quad * 8];
        bf16x8 aP1 = *(const bf16x8*)&sPw[l16 * LDP + 32 + quad * 8];
#pragma unroll
        for (int t = 0; t < 4; t++) {
            bf16x8 b0 = *(const bf16x8*)&sV[(l16 + 16 * t) * LDP + quad * 8];
            bf16x8 b1 = *(const bf16x8*)&sV[(l16 + 16 * t) * LDP + 32 + quad * 8];
            O[t] = __builtin_amdgcn_mfma_f32_16x16x32_bf16(aP0, b0, O[t], 0, 0, 0);
            O[t] = __builtin_amdgcn_mfma_f32_16x16x32_bf16(aP1, b1, O[t], 0, 0, 0);
        }
    }

    // epilogue: av = O/l (bf16) -> W-GEMM -> relu(+res)
#pragma unroll
    for (int r = 0; r < 4; r++) {
        float invl = 1.0f / l_r[r];
#pragma unroll
        for (int t = 0; t < 4; t++)
            sPw[(quad * 4 + r) * LDP + l16 + 16 * t] = f2bf(O[t][r] * invl);
    }
    bf16x8 aA0 = *(const bf16x8*)&sPw[l16 * LDP + quad * 8];
    bf16x8 aA1 = *(const bf16x8*)&sPw[l16 * LDP + 32 + quad * 8];
    f32x4 R[4];
#pragma unroll
    for (int t = 0; t < 4; t++) {
        bf16x8 b0 = *(const bf16x8*)&sW[(l16 + 16 * t) * LDP + quad * 8];
        bf16x8 b1 = *(const bf16x8*)&sW[(l16 + 16 * t) * LDP + 32 + quad * 8];
        f32x4 acc = fzero;
        acc = __builtin_amdgcn_mfma_f32_16x16x32_bf16(aA0, b0, acc, 0, 0, 0);
        acc = __builtin_amdgcn_mfma_f32_16x16x32_bf16(aA1, b1, acc, 0, 0, 0);
        R[t] = acc;
    }
#pragma unroll
    for (int t = 0; t < 4; t++) {
#pragma unroll
        for (int r = 0; r < 4; r++) {
            int row = qt * BM + wave * 16 + quad * 4 + r;
            int col = l16 + 16 * t;
            size_t idx = ((size_t)bh * NSEQ + row) * DD + col;
            float rv = res_isf ? ((const float*)res)[idx] : bf2f(((const u16*)res)[idx]);
            float v = R[t][r] + rv;
            v = (v < 0.f) ? 0.f : v;       // NaN-transparent relu
            if (out_isf) ((float*)outp)[idx] = v;
            else         ((u16*)outp)[idx]  = f2bf(v);
        }
    }
}

extern "C" void kernel_launch(void* const* d_in, const int* in_sizes, int n_in,
                              void* d_out, int out_size, void* d_ws, size_t ws_size,
                              hipStream_t stream) {
    const float* x  = (const float*)d_in[0];
    const float* W1 = (const float*)d_in[1];
    const float* W2 = (const float*)d_in[2];
    const float* a1 = (const float*)d_in[3];
    const float* a2 = (const float*)d_in[4];
    float* outp = (float*)d_out;

    size_t elems = (size_t)BH * NSEQ * DD;         // 4,194,304
    u16* xn = (u16*)d_ws;                          // 8.39 MB
    u16* xT = xn + elems;                          // 8.39 MB
    u16* y1 = xT + elems;                          // 8.39 MB (layer-1 out, bf16)

    dim3 pgrid(BH * 16),     pblk(256);
    dim3 agrid(BH * QTILES), ablk(256);

    // layer 1: x (fp32) -> y1 (bf16)
    ContentGCN_5059471475267_prep<<<pgrid, pblk, 0, stream>>>(x, 1, xn, xT);
    ContentGCN_5059471475267_attn<<<agrid, ablk, 0, stream>>>(xn, xT, x, 1, W1, a1, y1, 0);
    // layer 2: y1 (bf16) -> d_out (fp32)
    ContentGCN_5059471475267_prep<<<pgrid, pblk, 0, stream>>>(y1, 0, xn, xT);
    ContentGCN_5059471475267_attn<<<agrid, ablk, 0, stream>>>(xn, xT, y1, 0, W2, a2, outp, 1);
}

// Round 8
// 372.788 us; speedup vs baseline: 18.1655x; 1.6298x over previous
//
#include <hip/hip_runtime.h>

typedef unsigned short u16;
typedef unsigned int   u32;
typedef __bf16 bf16x8 __attribute__((ext_vector_type(8)));  // MFMA A/B (4 VGPRs)
typedef float  f32x4  __attribute__((ext_vector_type(4)));  // MFMA C/D

#define BH    16
#define NSEQ  4096
#define DD    64
#define BM    64            // Q rows per block (4 waves x 16)
#define BN    64            // K rows per tile
#define LDP   72            // LDS row stride (u16): b128 access = uniform 8/bank
#define NT    (NSEQ / BN)   // 64 K-tiles
#define QTILES (NSEQ / BM)  // 64

__device__ __forceinline__ float bf2f(u16 u) {
    union { u32 i; float f; } v; v.i = ((u32)u) << 16; return v.f;
}
__device__ __forceinline__ u16 f2bf(float f) {          // true RNE (prep path)
    union { float f; u32 i; } v; v.f = f;
    u32 r = v.i + 0x7fffu + ((v.i >> 16) & 1u);
    return (u16)(r >> 16);
}
__device__ __forceinline__ u16 f2bf_fast(float f) {     // round-half-up, 2 VALU ops
    union { float f; u32 i; } v; v.f = f;
    return (u16)((v.i + 0x8000u) >> 16);
}

// ---------------------------------------------------------------------------
// prep: L2-normalize rows -> xn (bf16); transpose raw values -> xT (bf16)
// isf=1: src fp32; isf=0: src bf16. grid BH*16 x 256 (1 row/thread)
// ---------------------------------------------------------------------------
__global__ __launch_bounds__(256) void ContentGCN_5059471475267_prep(
    const void* __restrict__ src, int isf,
    u16* __restrict__ xn, u16* __restrict__ xT)
{
    __shared__ u16 tile[256 * 65];
    int bh = blockIdx.x >> 4, nt = blockIdx.x & 15, tid = threadIdx.x;
    size_t base = ((size_t)bh * NSEQ + nt * 256 + tid) * DD;

    float v[64];
    if (isf) {
        const float4* g = (const float4*)((const float*)src + base);
#pragma unroll
        for (int i = 0; i < 16; i++) {
            float4 t4 = g[i];
            v[4*i] = t4.x; v[4*i+1] = t4.y; v[4*i+2] = t4.z; v[4*i+3] = t4.w;
        }
    } else {
        alignas(16) u16 tmp[64];
        const uint4* g = (const uint4*)((const u16*)src + base);
#pragma unroll
        for (int i = 0; i < 8; i++) ((uint4*)tmp)[i] = g[i];
#pragma unroll
        for (int d = 0; d < 64; d++) v[d] = bf2f(tmp[d]);
    }

    float ss = 0.f;
#pragma unroll
    for (int d = 0; d < 64; d++) ss += v[d] * v[d];
    float n = sqrtf(ss);
    if (n < 1e-12f) n = 1e-12f;            // F.normalize eps
    float inv = 1.0f / n;

    alignas(16) u16 nb[64];
#pragma unroll
    for (int d = 0; d < 64; d++) nb[d] = f2bf(v[d] * inv);
    uint4* gn = (uint4*)(xn + base);
#pragma unroll
    for (int i = 0; i < 8; i++) gn[i] = ((uint4*)nb)[i];

#pragma unroll
    for (int d = 0; d < 64; d++) tile[tid * 65 + d] = f2bf(v[d]);
    __syncthreads();

    int d = tid & 63, ch = tid >> 6;
    alignas(16) u16 ob[64];
#pragma unroll
    for (int nn = 0; nn < 64; nn++) ob[nn] = tile[(ch * 64 + nn) * 65 + d];
    uint4* gt = (uint4*)(xT + ((size_t)bh * DD + d) * NSEQ + (size_t)nt * 256 + ch * 64);
#pragma unroll
    for (int i = 0; i < 8; i++) gt[i] = ((uint4*)ob)[i];
}

// ---------------------------------------------------------------------------
// attn: MFMA flash attention, FIXED-max softmax (diag cosine == 1), register
// prefetch of K/V staging. out = relu(av@W^T + res). W staged into sK at
// epilogue (sW eliminated -> 27.6 KB LDS -> 5 blocks/CU).
// ---------------------------------------------------------------------------
__global__ __launch_bounds__(256) void ContentGCN_5059471475267_attn(
    const u16* __restrict__ xn, const u16* __restrict__ xT,
    const void* __restrict__ res, int res_isf,
    const float* __restrict__ Wt, const float* __restrict__ alphap,
    void* __restrict__ outp, int out_isf)
{
    __shared__ u16 sK[BN * LDP];        // K tile; W at epilogue
    __shared__ u16 sV[DD * LDP];        // V^T: [d][k]
    __shared__ u16 sP[4 * 16 * LDP];    // wave-private P strips

    int tid  = threadIdx.x;
    int wave = tid >> 6, lane = tid & 63;
    int quad = lane >> 4, l16 = lane & 15;
    int bh   = blockIdx.x >> 6;
    int qt   = blockIdx.x & 63;

    float scale = 1.4426950408889634f / fmaxf(alphap[0], 0.01f);  // exp2 domain

    // Q fragments (A-layout: m=l16, k=quad*8+j)
    int qrow = qt * BM + wave * 16 + l16;
    size_t qbase = ((size_t)bh * NSEQ + qrow) * DD;
    bf16x8 aQ0 = *(const bf16x8*)(xn + qbase + quad * 8);
    bf16x8 aQ1 = *(const bf16x8*)(xn + qbase + 32 + quad * 8);

    const f32x4 fzero = {0.f, 0.f, 0.f, 0.f};
    f32x4 O[4];
#pragma unroll
    for (int t = 0; t < 4; t++) O[t] = fzero;
    float l_r[4] = {0.f, 0.f, 0.f, 0.f};   // per-lane partial softmax sums

    u16* sPw = sP + wave * (16 * LDP);
    int srow = tid >> 2, scol = (tid & 3) * 16;   // staging: 16 u16/thread

    // prefetch tile 0 into registers
    const uint4* gk = (const uint4*)(xn + ((size_t)bh * NSEQ + srow) * DD + scol);
    const uint4* gv = (const uint4*)(xT + ((size_t)bh * DD + srow) * NSEQ + scol);
    uint4 ck0 = gk[0], ck1 = gk[1];
    uint4 cv0 = gv[0], cv1 = gv[1];

    for (int kt = 0; kt < NT; kt++) {
        __syncthreads();   // prior tile's LDS reads complete before overwrite
        *(uint4*)&sK[srow * LDP + scol]     = ck0;
        *(uint4*)&sK[srow * LDP + scol + 8] = ck1;
        *(uint4*)&sV[srow * LDP + scol]     = cv0;
        *(uint4*)&sV[srow * LDP + scol + 8] = cv1;
        {   // prefetch next tile (clamped on last iter; loads overlap compute)
            int ktn = (kt + 1 < NT) ? kt + 1 : kt;
            const uint4* nk = (const uint4*)(xn + ((size_t)bh * NSEQ + (size_t)ktn * BN + srow) * DD + scol);
            const uint4* nv = (const uint4*)(xT + ((size_t)bh * DD + srow) * NSEQ + (size_t)ktn * BN + scol);
            ck0 = nk[0]; ck1 = nk[1];
            cv0 = nv[0]; cv1 = nv[1];
        }
        __syncthreads();

        // S = Qn @ Kn^T (16 rows x 64 cols per wave)
        f32x4 S[4];
#pragma unroll
        for (int t = 0; t < 4; t++) {
            bf16x8 b0 = *(const bf16x8*)&sK[(l16 + 16 * t) * LDP + quad * 8];
            bf16x8 b1 = *(const bf16x8*)&sK[(l16 + 16 * t) * LDP + 32 + quad * 8];
            f32x4 acc = fzero;
            acc = __builtin_amdgcn_mfma_f32_16x16x32_bf16(aQ0, b0, acc, 0, 0, 0);
            acc = __builtin_amdgcn_mfma_f32_16x16x32_bf16(aQ1, b1, acc, 0, 0, 0);
            S[t] = acc;
        }

        // fixed-max softmax: max cosine == diag == ~1, so m := scale statically.
        // p = exp2(s*scale - scale); no rescale, no per-iter reductions.
#pragma unroll
        for (int r = 0; r < 4; r++) {
            float ps = 0.f;
#pragma unroll
            for (int t = 0; t < 4; t++) {
                float p = exp2f(fmaf(S[t][r], scale, -scale));
                ps += p;
                sPw[(quad * 4 + r) * LDP + l16 + 16 * t] = f2bf_fast(p);
            }
            l_r[r] += ps;
        }

        // PV: A = P (LDS round-trip to A-layout), B = V^T rows
        bf16x8 aP0 = *(const bf16x8*)&sPw[l16 * LDP + quad * 8];
        bf16x8 aP1 = *(const bf16x8*)&sPw[l16 * LDP + 32 + quad * 8];
#pragma unroll
        for (int t = 0; t < 4; t++) {
            bf16x8 b0 = *(const bf16x8*)&sV[(l16 + 16 * t) * LDP + quad * 8];
            bf16x8 b1 = *(const bf16x8*)&sV[(l16 + 16 * t) * LDP + 32 + quad * 8];
            O[t] = __builtin_amdgcn_mfma_f32_16x16x32_bf16(aP0, b0, O[t], 0, 0, 0);
            O[t] = __builtin_amdgcn_mfma_f32_16x16x32_bf16(aP1, b1, O[t], 0, 0, 0);
        }
    }

    // deferred l reduction (16 lanes per row group) + av -> sPw (bf16)
#pragma unroll
    for (int r = 0; r < 4; r++) {
        float l = l_r[r];
        l += __shfl_xor(l, 1);
        l += __shfl_xor(l, 2);
        l += __shfl_xor(l, 4);
        l += __shfl_xor(l, 8);
        float invl = 1.0f / l;
#pragma unroll
        for (int t = 0; t < 4; t++)
            sPw[(quad * 4 + r) * LDP + l16 + 16 * t] = f2bf_fast(O[t][r] * invl);
    }
    bf16x8 aA0 = *(const bf16x8*)&sPw[l16 * LDP + quad * 8];
    bf16x8 aA1 = *(const bf16x8*)&sPw[l16 * LDP + 32 + quad * 8];

    // stage W (fp32 -> bf16) into sK (dead after loop; barrier both sides)
    __syncthreads();
    {
        int r = tid >> 2, c0 = (tid & 3) * 16;
        alignas(16) u16 wb[16];
        const float4* gw = (const float4*)(Wt + r * DD + c0);
#pragma unroll
        for (int i = 0; i < 4; i++) {
            float4 t4 = gw[i];
            wb[4*i]   = f2bf(t4.x); wb[4*i+1] = f2bf(t4.y);
            wb[4*i+2] = f2bf(t4.z); wb[4*i+3] = f2bf(t4.w);
        }
        *(uint4*)&sK[r * LDP + c0]     = ((uint4*)wb)[0];
        *(uint4*)&sK[r * LDP + c0 + 8] = ((uint4*)wb)[1];
    }
    __syncthreads();

    f32x4 R[4];
#pragma unroll
    for (int t = 0; t < 4; t++) {
        bf16x8 b0 = *(const bf16x8*)&sK[(l16 + 16 * t) * LDP + quad * 8];
        bf16x8 b1 = *(const bf16x8*)&sK[(l16 + 16 * t) * LDP + 32 + quad * 8];
        f32x4 acc = fzero;
        acc = __builtin_amdgcn_mfma_f32_16x16x32_bf16(aA0, b0, acc, 0, 0, 0);
        acc = __builtin_amdgcn_mfma_f32_16x16x32_bf16(aA1, b1, acc, 0, 0, 0);
        R[t] = acc;
    }
#pragma unroll
    for (int t = 0; t < 4; t++) {
#pragma unroll
        for (int r = 0; r < 4; r++) {
            int row = qt * BM + wave * 16 + quad * 4 + r;
            int col = l16 + 16 * t;
            size_t idx = ((size_t)bh * NSEQ + row) * DD + col;
            float rv = res_isf ? ((const float*)res)[idx] : bf2f(((const u16*)res)[idx]);
            float v = R[t][r] + rv;
            v = (v < 0.f) ? 0.f : v;       // NaN-transparent relu
            if (out_isf) ((float*)outp)[idx] = v;
            else         ((u16*)outp)[idx]  = f2bf(v);
        }
    }
}

extern "C" void kernel_launch(void* const* d_in, const int* in_sizes, int n_in,
                              void* d_out, int out_size, void* d_ws, size_t ws_size,
                              hipStream_t stream) {
    const float* x  = (const float*)d_in[0];
    const float* W1 = (const float*)d_in[1];
    const float* W2 = (const float*)d_in[2];
    const float* a1 = (const float*)d_in[3];
    const float* a2 = (const float*)d_in[4];
    float* outp = (float*)d_out;

    size_t elems = (size_t)BH * NSEQ * DD;         // 4,194,304
    u16* xn = (u16*)d_ws;                          // 8.39 MB
    u16* xT = xn + elems;                          // 8.39 MB
    u16* y1 = xT + elems;                          // 8.39 MB (layer-1 out, bf16)

    dim3 pgrid(BH * 16),     pblk(256);
    dim3 agrid(BH * QTILES), ablk(256);

    // layer 1: x (fp32) -> y1 (bf16)
    ContentGCN_5059471475267_prep<<<pgrid, pblk, 0, stream>>>(x, 1, xn, xT);
    ContentGCN_5059471475267_attn<<<agrid, ablk, 0, stream>>>(xn, xT, x, 1, W1, a1, y1, 0);
    // layer 2: y1 (bf16) -> d_out (fp32)
    ContentGCN_5059471475267_prep<<<pgrid, pblk, 0, stream>>>(y1, 0, xn, xT);
    ContentGCN_5059471475267_attn<<<agrid, ablk, 0, stream>>>(xn, xT, y1, 0, W2, a2, outp, 1);
}

// Round 9
// 348.180 us; speedup vs baseline: 19.4494x; 1.0707x over previous
//
#include <hip/hip_runtime.h>

typedef unsigned short u16;
typedef unsigned int   u32;
typedef __bf16 bf16x8 __attribute__((ext_vector_type(8)));  // MFMA A/B (4 VGPRs)
typedef float  f32x4  __attribute__((ext_vector_type(4)));  // MFMA C/D

#define BH    16
#define NSEQ  4096
#define DD    64
#define BM    64            // Q rows per block (4 waves x 16)
#define BN    64            // K rows per tile
#define LDP   72            // K/V LDS row stride (u16): b128 ops uniform 8/bank (min)
#define LDPP  68            // P-strip row stride (u16): u16 writes 2/bank (free), b64 reads 4/bank (min)
#define NT    (NSEQ / BN)   // 64 K-tiles
#define QTILES (NSEQ / BM)  // 64

__device__ __forceinline__ float bf2f(u16 u) {
    union { u32 i; float f; } v; v.i = ((u32)u) << 16; return v.f;
}
__device__ __forceinline__ u16 f2bf(float f) {          // true RNE (prep path)
    union { float f; u32 i; } v; v.f = f;
    u32 r = v.i + 0x7fffu + ((v.i >> 16) & 1u);
    return (u16)(r >> 16);
}
__device__ __forceinline__ u16 f2bf_fast(float f) {     // round-half-up, 2 VALU ops
    union { float f; u32 i; } v; v.f = f;
    return (u16)((v.i + 0x8000u) >> 16);
}
#if __has_builtin(__builtin_amdgcn_exp2f)
__device__ __forceinline__ float exp2_raw(float x) { return __builtin_amdgcn_exp2f(x); }
#else
__device__ __forceinline__ float exp2_raw(float x) {
    float r; asm("v_exp_f32 %0, %1" : "=v"(r) : "v"(x)); return r;
}
#endif

// ---------------------------------------------------------------------------
// prep: L2-normalize rows -> xn (bf16); transpose raw values -> xT (bf16)
// isf=1: src fp32; isf=0: src bf16. grid BH*16 x 256 (1 row/thread)
// ---------------------------------------------------------------------------
__global__ __launch_bounds__(256) void ContentGCN_5059471475267_prep(
    const void* __restrict__ src, int isf,
    u16* __restrict__ xn, u16* __restrict__ xT)
{
    __shared__ u16 tile[256 * 65];
    int bh = blockIdx.x >> 4, nt = blockIdx.x & 15, tid = threadIdx.x;
    size_t base = ((size_t)bh * NSEQ + nt * 256 + tid) * DD;

    float v[64];
    if (isf) {
        const float4* g = (const float4*)((const float*)src + base);
#pragma unroll
        for (int i = 0; i < 16; i++) {
            float4 t4 = g[i];
            v[4*i] = t4.x; v[4*i+1] = t4.y; v[4*i+2] = t4.z; v[4*i+3] = t4.w;
        }
    } else {
        alignas(16) u16 tmp[64];
        const uint4* g = (const uint4*)((const u16*)src + base);
#pragma unroll
        for (int i = 0; i < 8; i++) ((uint4*)tmp)[i] = g[i];
#pragma unroll
        for (int d = 0; d < 64; d++) v[d] = bf2f(tmp[d]);
    }

    float ss = 0.f;
#pragma unroll
    for (int d = 0; d < 64; d++) ss += v[d] * v[d];
    float n = sqrtf(ss);
    if (n < 1e-12f) n = 1e-12f;            // F.normalize eps
    float inv = 1.0f / n;

    alignas(16) u16 nb[64];
#pragma unroll
    for (int d = 0; d < 64; d++) nb[d] = f2bf(v[d] * inv);
    uint4* gn = (uint4*)(xn + base);
#pragma unroll
    for (int i = 0; i < 8; i++) gn[i] = ((uint4*)nb)[i];

#pragma unroll
    for (int d = 0; d < 64; d++) tile[tid * 65 + d] = f2bf(v[d]);
    __syncthreads();

    int d = tid & 63, ch = tid >> 6;
    alignas(16) u16 ob[64];
#pragma unroll
    for (int nn = 0; nn < 64; nn++) ob[nn] = tile[(ch * 64 + nn) * 65 + d];
    uint4* gt = (uint4*)(xT + ((size_t)bh * DD + d) * NSEQ + (size_t)nt * 256 + ch * 64);
#pragma unroll
    for (int i = 0; i < 8; i++) gt[i] = ((uint4*)ob)[i];
}

// ---------------------------------------------------------------------------
// attn: MFMA flash attention, fixed-max softmax (diag cosine == 1), register
// prefetch staging, conflict-free P strips (LDPP=68). out = relu(av@W^T+res).
// W staged into sK at epilogue (27.1 KB LDS).
// ---------------------------------------------------------------------------
__global__ __launch_bounds__(256) void ContentGCN_5059471475267_attn(
    const u16* __restrict__ xn, const u16* __restrict__ xT,
    const void* __restrict__ res, int res_isf,
    const float* __restrict__ Wt, const float* __restrict__ alphap,
    void* __restrict__ outp, int out_isf)
{
    __shared__ u16 sK[BN * LDP];        // K tile; W at epilogue
    __shared__ u16 sV[DD * LDP];        // V^T: [d][k]
    __shared__ u16 sP[4 * 16 * LDPP];   // wave-private P strips

    int tid  = threadIdx.x;
    int wave = tid >> 6, lane = tid & 63;
    int quad = lane >> 4, l16 = lane & 15;
    int bh   = blockIdx.x >> 6;
    int qt   = blockIdx.x & 63;

    float scale = 1.4426950408889634f / fmaxf(alphap[0], 0.01f);  // exp2 domain

    // Q fragments (A-layout: m=l16, k=quad*8+j)
    int qrow = qt * BM + wave * 16 + l16;
    size_t qbase = ((size_t)bh * NSEQ + qrow) * DD;
    bf16x8 aQ0 = *(const bf16x8*)(xn + qbase + quad * 8);
    bf16x8 aQ1 = *(const bf16x8*)(xn + qbase + 32 + quad * 8);

    const f32x4 fzero = {0.f, 0.f, 0.f, 0.f};
    f32x4 O[4];
#pragma unroll
    for (int t = 0; t < 4; t++) O[t] = fzero;
    float l_r[4] = {0.f, 0.f, 0.f, 0.f};   // per-lane partial softmax sums

    u16* sPw = sP + wave * (16 * LDPP);
    int srow = tid >> 2, scol = (tid & 3) * 16;   // staging: 16 u16/thread

    // staging pointers, bumped by constants each iter (no per-iter rebuild)
    const u16* pk = xn + ((size_t)bh * NSEQ + srow) * DD + scol;   // += BN*DD
    const u16* pv = xT + ((size_t)bh * DD + srow) * NSEQ + scol;   // += BN
    uint4 ck0 = ((const uint4*)pk)[0], ck1 = ((const uint4*)pk)[1];
    uint4 cv0 = ((const uint4*)pv)[0], cv1 = ((const uint4*)pv)[1];
    pk += (size_t)BN * DD; pv += BN;

    for (int kt = 0; kt < NT; kt++) {
        __syncthreads();   // prior tile's LDS reads complete before overwrite
        *(uint4*)&sK[srow * LDP + scol]     = ck0;
        *(uint4*)&sK[srow * LDP + scol + 8] = ck1;
        *(uint4*)&sV[srow * LDP + scol]     = cv0;
        *(uint4*)&sV[srow * LDP + scol + 8] = cv1;
        if (kt + 1 < NT) {   // prefetch next tile (overlaps compute)
            ck0 = ((const uint4*)pk)[0]; ck1 = ((const uint4*)pk)[1];
            cv0 = ((const uint4*)pv)[0]; cv1 = ((const uint4*)pv)[1];
            pk += (size_t)BN * DD; pv += BN;
        }
        __syncthreads();

        // S = Qn @ Kn^T (16 rows x 64 cols per wave)
        f32x4 S[4];
#pragma unroll
        for (int t = 0; t < 4; t++) {
            bf16x8 b0 = *(const bf16x8*)&sK[(l16 + 16 * t) * LDP + quad * 8];
            bf16x8 b1 = *(const bf16x8*)&sK[(l16 + 16 * t) * LDP + 32 + quad * 8];
            f32x4 acc = fzero;
            acc = __builtin_amdgcn_mfma_f32_16x16x32_bf16(aQ0, b0, acc, 0, 0, 0);
            acc = __builtin_amdgcn_mfma_f32_16x16x32_bf16(aQ1, b1, acc, 0, 0, 0);
            S[t] = acc;
        }

        // fixed-max softmax: p = exp2(s*scale - scale); raw v_exp_f32
#pragma unroll
        for (int r = 0; r < 4; r++) {
            float ps = 0.f;
#pragma unroll
            for (int t = 0; t < 4; t++) {
                float p = exp2_raw(fmaf(S[t][r], scale, -scale));
                ps += p;
                sPw[(quad * 4 + r) * LDPP + l16 + 16 * t] = f2bf_fast(p);
            }
            l_r[r] += ps;
        }

        // PV: A = P (LDS round-trip, b64 pairs), B = V^T rows
        union { uint2 u[2]; bf16x8 v; } pA0, pA1;
        pA0.u[0] = *(const uint2*)&sPw[l16 * LDPP + quad * 8];
        pA0.u[1] = *(const uint2*)&sPw[l16 * LDPP + quad * 8 + 4];
        pA1.u[0] = *(const uint2*)&sPw[l16 * LDPP + 32 + quad * 8];
        pA1.u[1] = *(const uint2*)&sPw[l16 * LDPP + 32 + quad * 8 + 4];
#pragma unroll
        for (int t = 0; t < 4; t++) {
            bf16x8 b0 = *(const bf16x8*)&sV[(l16 + 16 * t) * LDP + quad * 8];
            bf16x8 b1 = *(const bf16x8*)&sV[(l16 + 16 * t) * LDP + 32 + quad * 8];
            O[t] = __builtin_amdgcn_mfma_f32_16x16x32_bf16(pA0.v, b0, O[t], 0, 0, 0);
            O[t] = __builtin_amdgcn_mfma_f32_16x16x32_bf16(pA1.v, b1, O[t], 0, 0, 0);
        }
    }

    // deferred l reduction (16 lanes per row group) + av -> sPw (bf16)
#pragma unroll
    for (int r = 0; r < 4; r++) {
        float l = l_r[r];
        l += __shfl_xor(l, 1);
        l += __shfl_xor(l, 2);
        l += __shfl_xor(l, 4);
        l += __shfl_xor(l, 8);
        float invl = 1.0f / l;
#pragma unroll
        for (int t = 0; t < 4; t++)
            sPw[(quad * 4 + r) * LDPP + l16 + 16 * t] = f2bf_fast(O[t][r] * invl);
    }
    union { uint2 u[2]; bf16x8 v; } aA0, aA1;
    aA0.u[0] = *(const uint2*)&sPw[l16 * LDPP + quad * 8];
    aA0.u[1] = *(const uint2*)&sPw[l16 * LDPP + quad * 8 + 4];
    aA1.u[0] = *(const uint2*)&sPw[l16 * LDPP + 32 + quad * 8];
    aA1.u[1] = *(const uint2*)&sPw[l16 * LDPP + 32 + quad * 8 + 4];

    // stage W (fp32 -> bf16) into sK (dead after loop; barrier both sides)
    __syncthreads();
    {
        int r = tid >> 2, c0 = (tid & 3) * 16;
        alignas(16) u16 wb[16];
        const float4* gw = (const float4*)(Wt + r * DD + c0);
#pragma unroll
        for (int i = 0; i < 4; i++) {
            float4 t4 = gw[i];
            wb[4*i]   = f2bf(t4.x); wb[4*i+1] = f2bf(t4.y);
            wb[4*i+2] = f2bf(t4.z); wb[4*i+3] = f2bf(t4.w);
        }
        *(uint4*)&sK[r * LDP + c0]     = ((uint4*)wb)[0];
        *(uint4*)&sK[r * LDP + c0 + 8] = ((uint4*)wb)[1];
    }
    __syncthreads();

    f32x4 R[4];
#pragma unroll
    for (int t = 0; t < 4; t++) {
        bf16x8 b0 = *(const bf16x8*)&sK[(l16 + 16 * t) * LDP + quad * 8];
        bf16x8 b1 = *(const bf16x8*)&sK[(l16 + 16 * t) * LDP + 32 + quad * 8];
        f32x4 acc = fzero;
        acc = __builtin_amdgcn_mfma_f32_16x16x32_bf16(aA0.v, b0, acc, 0, 0, 0);
        acc = __builtin_amdgcn_mfma_f32_16x16x32_bf16(aA1.v, b1, acc, 0, 0, 0);
        R[t] = acc;
    }
#pragma unroll
    for (int t = 0; t < 4; t++) {
#pragma unroll
        for (int r = 0; r < 4; r++) {
            int row = qt * BM + wave * 16 + quad * 4 + r;
            int col = l16 + 16 * t;
            size_t idx = ((size_t)bh * NSEQ + row) * DD + col;
            float rv = res_isf ? ((const float*)res)[idx] : bf2f(((const u16*)res)[idx]);
            float v = R[t][r] + rv;
            v = (v < 0.f) ? 0.f : v;       // NaN-transparent relu
            if (out_isf) ((float*)outp)[idx] = v;
            else         ((u16*)outp)[idx]  = f2bf(v);
        }
    }
}

extern "C" void kernel_launch(void* const* d_in, const int* in_sizes, int n_in,
                              void* d_out, int out_size, void* d_ws, size_t ws_size,
                              hipStream_t stream) {
    const float* x  = (const float*)d_in[0];
    const float* W1 = (const float*)d_in[1];
    const float* W2 = (const float*)d_in[2];
    const float* a1 = (const float*)d_in[3];
    const float* a2 = (const float*)d_in[4];
    float* outp = (float*)d_out;

    size_t elems = (size_t)BH * NSEQ * DD;         // 4,194,304
    u16* xn = (u16*)d_ws;                          // 8.39 MB
    u16* xT = xn + elems;                          // 8.39 MB
    u16* y1 = xT + elems;                          // 8.39 MB (layer-1 out, bf16)

    dim3 pgrid(BH * 16),     pblk(256);
    dim3 agrid(BH * QTILES), ablk(256);

    // layer 1: x (fp32) -> y1 (bf16)
    ContentGCN_5059471475267_prep<<<pgrid, pblk, 0, stream>>>(x, 1, xn, xT);
    ContentGCN_5059471475267_attn<<<agrid, ablk, 0, stream>>>(xn, xT, x, 1, W1, a1, y1, 0);
    // layer 2: y1 (bf16) -> d_out (fp32)
    ContentGCN_5059471475267_prep<<<pgrid, pblk, 0, stream>>>(y1, 0, xn, xT);
    ContentGCN_5059471475267_attn<<<agrid, ablk, 0, stream>>>(xn, xT, y1, 0, W2, a2, outp, 1);
}